// Round 3
// baseline (975.428 us; speedup 1.0000x reference)
//
#include <hip/hip_runtime.h>

#define N_NODES 65536
#define IN_FEAT 16
#define HIDDEN 32
#define NUM_EDGES 1048576
#define NUM_GRAPHS 16
#define NODES_PER_GRAPH 4096
#define FC1_IN (NODES_PER_GRAPH * HIDDEN) /* 131072 */
#define FC1_OUT 256
#define FC2_OUT 64
#define FC1_KCHUNK 128
#define FC1_NCHUNK (FC1_IN / FC1_KCHUNK) /* 1024 */
#define NB 256          /* buckets = dst>>8 */
#define BUCKET_CAP 5120 /* mean 4096, sd 64 -> 16 sigma headroom */
#define NBLK 512        /* persistent grid: 2 blocks/CU, co-resident */
#define EPB_A (NUM_EDGES / NBLK) /* 2048 edges per phase-A block */
#define CTRL_BYTES 20480 /* bar[16] + cursor[256] + fc1accum[4096] */

typedef _Float16 half8 __attribute__((ext_vector_type(8)));  // 16 B
typedef _Float16 half4 __attribute__((ext_vector_type(4)));  // 8 B

// device-scope grid barrier: counters pre-zeroed by hipMemsetAsync.
// All NBLK blocks are co-resident (2/CU: 17KB LDS, <=256 VGPR), so spinning
// is deadlock-free. Agent-scope atomics + threadfence give cross-XCD
// visibility (per-XCD L2 not coherent).
__device__ __forceinline__ void gridbar(int* bar, int id) {
    __syncthreads();
    if (threadIdx.x == 0) {
        __threadfence();
        __hip_atomic_fetch_add(&bar[id], 1, __ATOMIC_ACQ_REL, __HIP_MEMORY_SCOPE_AGENT);
        while (__hip_atomic_load(&bar[id], __ATOMIC_ACQUIRE, __HIP_MEMORY_SCOPE_AGENT) < NBLK)
            __builtin_amdgcn_s_sleep(8);
        __threadfence();
    }
    __syncthreads();
}

// ---- fused gather+matmul phase (verbatim port of gmm_kernel body) ----
// LPN = 2*F8 lanes per node: f8 = feature chunk, h = edge-list half.
template <int FIN, bool LAST>
__device__ __forceinline__ void gmm_phase(const int* __restrict__ rowstart,
                                          const int* __restrict__ rowend,
                                          const unsigned short* __restrict__ csr,
                                          const half8* __restrict__ p,
                                          const float* __restrict__ W,
                                          const float* __restrict__ bias,
                                          const float* __restrict__ dinv,
                                          void* __restrict__ outp,
                                          float4* Ws4, float4* bs4) {
    constexpr int F8 = FIN / 8;
    constexpr int LOG2F8 = (FIN == 16) ? 1 : 2;
    constexpr int LPN = 2 * F8;
    constexpr int LOG2LPN = LOG2F8 + 1;
    constexpr int NOUT4 = 8 / LPN;
    constexpr int NTASK = N_NODES * LPN;
    constexpr int NITER = NTASK / (NBLK * 256);  // 2 (L1) or 4 (L2/L3)
    int t = threadIdx.x;
    for (int i = t; i < FIN * 8; i += 256) Ws4[i] = ((const float4*)W)[i];
    if (t < 8) bs4[t] = ((const float4*)bias)[t];
    __syncthreads();

    int f8 = t & (F8 - 1);
    int h = (t >> LOG2F8) & 1;
    int fo0 = (t & (LPN - 1)) * NOUT4;

    for (int it = 0; it < NITER; ++it) {
        int task = blockIdx.x * 256 + t + it * (NBLK * 256);
        int n = task >> LOG2LPN;

        float acc[8];
        if (h == 0) {
            half8 self = p[(size_t)n * F8 + f8];
#pragma unroll
            for (int e = 0; e < 8; e++) acc[e] = (float)self[e];
        } else {
#pragma unroll
            for (int e = 0; e < 8; e++) acc[e] = 0.f;
        }
        int beg0 = rowstart[n];
        int end0 = rowend[n];
        int halfc = (end0 - beg0 + 1) >> 1;
        int beg = beg0 + h * halfc;
        int end = h ? end0 : (beg0 + halfc);
        int i = beg;
        for (; i + 8 <= end; i += 8) {
            int s[8];
#pragma unroll
            for (int u = 0; u < 8; u++) s[u] = csr[i + u];
            half8 a[8];
#pragma unroll
            for (int u = 0; u < 8; u++) a[u] = p[(size_t)s[u] * F8 + f8];
#pragma unroll
            for (int u = 0; u < 8; u++)
#pragma unroll
                for (int e = 0; e < 8; e++) acc[e] += (float)a[u][e];
        }
        if (i + 4 <= end) {
            int s[4];
#pragma unroll
            for (int u = 0; u < 4; u++) s[u] = csr[i + u];
            half8 a[4];
#pragma unroll
            for (int u = 0; u < 4; u++) a[u] = p[(size_t)s[u] * F8 + f8];
#pragma unroll
            for (int u = 0; u < 4; u++)
#pragma unroll
                for (int e = 0; e < 8; e++) acc[e] += (float)a[u][e];
            i += 4;
        }
        for (; i < end; i++) {
            half8 a = p[(size_t)csr[i] * F8 + f8];
#pragma unroll
            for (int e = 0; e < 8; e++) acc[e] += (float)a[e];
        }

        // combine edge halves (lanes h and h^1, distance F8)
#pragma unroll
        for (int e = 0; e < 8; e++) acc[e] += __shfl_xor(acc[e], F8);

        // butterfly: lane gains all FIN q-features
        float a1[8], a2[8], a3[8];
#pragma unroll
        for (int e = 0; e < 8; e++) a1[e] = __shfl_xor(acc[e], 1);
        if (F8 == 4) {
#pragma unroll
            for (int e = 0; e < 8; e++) a2[e] = __shfl_xor(acc[e], 2);
#pragma unroll
            for (int e = 0; e < 8; e++) a3[e] = __shfl_xor(a1[e], 2);
        }

        float4 o4[NOUT4];
#pragma unroll
        for (int j = 0; j < NOUT4; j++) o4[j] = make_float4(0.f, 0.f, 0.f, 0.f);

#define MM_CHUNK(AR, C)                                               \
    {                                                                 \
        int c_ = (C);                                                 \
        _Pragma("unroll") for (int e = 0; e < 8; e++) {               \
            int fi = c_ * 8 + e;                                      \
            float r = (AR)[e];                                        \
            _Pragma("unroll") for (int j = 0; j < NOUT4; j++) {       \
                float4 wv = Ws4[fi * 8 + fo0 + j];                    \
                o4[j].x += r * wv.x;                                  \
                o4[j].y += r * wv.y;                                  \
                o4[j].z += r * wv.z;                                  \
                o4[j].w += r * wv.w;                                  \
            }                                                         \
        }                                                             \
    }

        MM_CHUNK(acc, f8)
        MM_CHUNK(a1, f8 ^ 1)
        if (F8 == 4) {
            MM_CHUNK(a2, f8 ^ 2)
            MM_CHUNK(a3, f8 ^ 3)
        }
#undef MM_CHUNK

        float di = dinv[n];
        float4 v4[NOUT4];
#pragma unroll
        for (int j = 0; j < NOUT4; j++) {
            float4 bb = bs4[fo0 + j];
            float4 v;
            v.x = o4[j].x * di + bb.x;
            v.y = o4[j].y * di + bb.y;
            v.z = o4[j].z * di + bb.z;
            v.w = o4[j].w * di + bb.w;
            v.x = v.x > 0.f ? v.x : 0.f;
            v.y = v.y > 0.f ? v.y : 0.f;
            v.z = v.z > 0.f ? v.z : 0.f;
            v.w = v.w > 0.f ? v.w : 0.f;
            v4[j] = v;
        }
        if (LAST) {
            float4* o = (float4*)outp;
#pragma unroll
            for (int j = 0; j < NOUT4; j++) o[(size_t)n * 8 + fo0 + j] = v4[j];
        } else {
            if constexpr (NOUT4 >= 2) {
                half8* o = (half8*)outp;  // row = 32 halfs = 4 half8
#pragma unroll
                for (int pr = 0; pr < NOUT4 / 2; pr++) {
                    float4 lo = v4[2 * pr], hi = v4[2 * pr + 1];
                    half8 hh;
                    hh[0] = (_Float16)(lo.x * di); hh[1] = (_Float16)(lo.y * di);
                    hh[2] = (_Float16)(lo.z * di); hh[3] = (_Float16)(lo.w * di);
                    hh[4] = (_Float16)(hi.x * di); hh[5] = (_Float16)(hi.y * di);
                    hh[6] = (_Float16)(hi.z * di); hh[7] = (_Float16)(hi.w * di);
                    o[(size_t)n * 4 + fo0 / 2 + pr] = hh;
                }
            } else {
                half4* o = (half4*)outp;
                float4 v = v4[0];
                half4 hh;
                hh[0] = (_Float16)(v.x * di); hh[1] = (_Float16)(v.y * di);
                hh[2] = (_Float16)(v.z * di); hh[3] = (_Float16)(v.w * di);
                o[(size_t)n * 8 + fo0] = hh;
            }
        }
    }
}

// ---- the whole pipeline in one persistent kernel ----
__global__ __launch_bounds__(256, 2) void mega_kernel(
    const float* __restrict__ x, const int* __restrict__ src, const int* __restrict__ dst,
    const float* __restrict__ W1, const float* __restrict__ b1,
    const float* __restrict__ W2, const float* __restrict__ b2,
    const float* __restrict__ W3, const float* __restrict__ b3,
    const float* __restrict__ fc1_w, const float* __restrict__ fc1_b,
    const float* __restrict__ fc2_w, const float* __restrict__ fc2_b,
    int* __restrict__ bar, int* __restrict__ bucket_cursor, float* __restrict__ fc1accum,
    int* __restrict__ binned, unsigned short* __restrict__ csr,
    int* __restrict__ rowstart, int* __restrict__ rowend, float* __restrict__ dinv,
    half8* __restrict__ p0, half8* __restrict__ pA, half8* __restrict__ pB,
    float* __restrict__ h3, float* __restrict__ out) {
    __shared__ int hist[NB];
    __shared__ int scanbuf[NB];
    __shared__ int startsh[NB];
    __shared__ int cursh[NB];
    __shared__ float4 Ws4[HIDDEN * 8];  // 4 KB, max FIN
    __shared__ float4 bs4[8];
    __shared__ float hs[NUM_GRAPHS * FC1_KCHUNK];  // 8 KB
    __shared__ float vs[FC1_OUT];                  // 1 KB

    int t = threadIdx.x;

    // ---- phase A: bin edges by dst>>8 (cursor pre-zeroed; base = b*CAP + cursor) ----
    {
        hist[t] = 0;
        __syncthreads();
        int e0 = blockIdx.x * EPB_A;
        int s[8], d[8];
#pragma unroll
        for (int i = 0; i < 8; i++) {
            int e = e0 + t + 256 * i;
            s[i] = src[e];
            d[i] = dst[e];
        }
#pragma unroll
        for (int i = 0; i < 8; i++) atomicAdd(&hist[d[i] >> 8], 1);
        __syncthreads();
        scanbuf[t] = t * BUCKET_CAP + atomicAdd(&bucket_cursor[t], hist[t]);  // base
        cursh[t] = 0;
        __syncthreads();
#pragma unroll
        for (int i = 0; i < 8; i++) {
            int b = d[i] >> 8;
            int r = atomicAdd(&cursh[b], 1);
            binned[scanbuf[b] + r] = s[i] | ((d[i] & 255) << 16);
        }
    }
    gridbar(bar, 0);

    // ---- phase B: per-bucket counting sort (blocks 0..255); emits csr/rows/dinv/p0 ----
    if (blockIdx.x < NB) {
        int b = blockIdx.x;
        int bbase = b * BUCKET_CAP;
        int cnt = bucket_cursor[b];  // cursor started at 0 -> holds count
        hist[t] = 0;
        __syncthreads();
        for (int i = t; i < cnt; i += 256) atomicAdd(&hist[binned[bbase + i] >> 16], 1);
        __syncthreads();
        int v = hist[t];
        scanbuf[t] = v;
        __syncthreads();
        for (int off = 1; off < NB; off <<= 1) {
            int y = (t >= off) ? scanbuf[t - off] : 0;
            __syncthreads();
            scanbuf[t] += y;
            __syncthreads();
        }
        startsh[t] = scanbuf[t] - v;
        cursh[t] = 0;
        __syncthreads();
        for (int i = t; i < cnt; i += 256) {
            int p = binned[bbase + i];
            int dl = p >> 16;
            int r = atomicAdd(&cursh[dl], 1);
            csr[bbase + startsh[dl] + r] = (unsigned short)(p & 0xFFFF);
        }
        int n = b * NB + t;
        int excl = startsh[t];
        rowstart[n] = bbase + excl;
        rowend[n] = bbase + excl + v;
        float di = rsqrtf((float)v + 1.0f);
        dinv[n] = di;
        // p0 prescale: thread t = node t of this bucket (2 half8 chunks)
        const float4* x4 = (const float4*)x;
        float4 a = x4[(size_t)n * 4 + 0];
        float4 c = x4[(size_t)n * 4 + 1];
        float4 e = x4[(size_t)n * 4 + 2];
        float4 f = x4[(size_t)n * 4 + 3];
        half8 h0, h1;
        h0[0] = (_Float16)(a.x * di); h0[1] = (_Float16)(a.y * di);
        h0[2] = (_Float16)(a.z * di); h0[3] = (_Float16)(a.w * di);
        h0[4] = (_Float16)(c.x * di); h0[5] = (_Float16)(c.y * di);
        h0[6] = (_Float16)(c.z * di); h0[7] = (_Float16)(c.w * di);
        h1[0] = (_Float16)(e.x * di); h1[1] = (_Float16)(e.y * di);
        h1[2] = (_Float16)(e.z * di); h1[3] = (_Float16)(e.w * di);
        h1[4] = (_Float16)(f.x * di); h1[5] = (_Float16)(f.y * di);
        h1[6] = (_Float16)(f.z * di); h1[7] = (_Float16)(f.w * di);
        p0[(size_t)n * 2 + 0] = h0;
        p0[(size_t)n * 2 + 1] = h1;
    }
    gridbar(bar, 1);

    // ---- gmm layers ----
    gmm_phase<IN_FEAT, false>(rowstart, rowend, csr, p0, W1, b1, dinv, pA, Ws4, bs4);
    gridbar(bar, 2);
    gmm_phase<HIDDEN, false>(rowstart, rowend, csr, pA, W2, b2, dinv, pB, Ws4, bs4);
    gridbar(bar, 3);
    gmm_phase<HIDDEN, true>(rowstart, rowend, csr, pB, W3, b3, dinv, h3, Ws4, bs4);
    gridbar(bar, 4);

    // ---- fc1: each block 2 kchunks, atomic-accumulate into fc1accum[16][256] ----
    {
        int kl = t & 3;
        int c = t >> 2;
        const float4* w4 = (const float4*)fc1_w;
        for (int kc = 0; kc < 2; ++kc) {
            int kbase = (blockIdx.x * 2 + kc) * FC1_KCHUNK;
            __syncthreads();  // protect hs reuse
            for (int i = t; i < NUM_GRAPHS * FC1_KCHUNK; i += 256) {
                int g = i >> 7;
                int kk = i & 127;
                hs[i] = h3[(size_t)g * FC1_IN + kbase + kk];
            }
            __syncthreads();
            float4 acc[NUM_GRAPHS];
#pragma unroll
            for (int g = 0; g < NUM_GRAPHS; g++) acc[g] = make_float4(0.f, 0.f, 0.f, 0.f);
            for (int i0 = 0; i0 < FC1_KCHUNK / 4; i0 += 4) {
                float4 wv[4];
#pragma unroll
                for (int u = 0; u < 4; u++)
                    wv[u] = w4[(size_t)(kbase + kl + 4 * (i0 + u)) * (FC1_OUT / 4) + c];
#pragma unroll
                for (int u = 0; u < 4; u++) {
                    int kk = kl + 4 * (i0 + u);
#pragma unroll
                    for (int g = 0; g < NUM_GRAPHS; g++) {
                        float hg = hs[g * FC1_KCHUNK + kk];
                        acc[g].x += hg * wv[u].x;
                        acc[g].y += hg * wv[u].y;
                        acc[g].z += hg * wv[u].z;
                        acc[g].w += hg * wv[u].w;
                    }
                }
            }
#pragma unroll
            for (int g = 0; g < NUM_GRAPHS; g++) {
                acc[g].x += __shfl_xor(acc[g].x, 1);
                acc[g].y += __shfl_xor(acc[g].y, 1);
                acc[g].z += __shfl_xor(acc[g].z, 1);
                acc[g].w += __shfl_xor(acc[g].w, 1);
                acc[g].x += __shfl_xor(acc[g].x, 2);
                acc[g].y += __shfl_xor(acc[g].y, 2);
                acc[g].z += __shfl_xor(acc[g].z, 2);
                acc[g].w += __shfl_xor(acc[g].w, 2);
            }
            if (kl == 0) {
#pragma unroll
                for (int g = 0; g < NUM_GRAPHS; g++) {
                    float* dstp = &fc1accum[g * FC1_OUT + c * 4];
                    atomicAdd(dstp + 0, acc[g].x);
                    atomicAdd(dstp + 1, acc[g].y);
                    atomicAdd(dstp + 2, acc[g].z);
                    atomicAdd(dstp + 3, acc[g].w);
                }
            }
        }
    }
    gridbar(bar, 5);

    // ---- fc2: blocks 0..15 (one graph each) ----
    if (blockIdx.x < NUM_GRAPHS) {
        int g = blockIdx.x;
        for (int k = t; k < FC1_OUT; k += 256) {
            float s = fc1accum[g * FC1_OUT + k] + fc1_b[k];
            vs[k] = s > 0.f ? s : 0.f;
        }
        __syncthreads();
        if (t < FC2_OUT) {
            int j = t;
            float acc = fc2_b[j];
            for (int k = 0; k < FC1_OUT; k++) acc += vs[k] * fc2_w[k * FC2_OUT + j];
            out[g * FC2_OUT + j] = acc;
        }
    }
}

extern "C" void kernel_launch(void* const* d_in, const int* in_sizes, int n_in,
                              void* d_out, int out_size, void* d_ws, size_t ws_size,
                              hipStream_t stream) {
    const float* x = (const float*)d_in[0];
    const int* ei = (const int*)d_in[1];
    const int* src = ei;
    const int* dst = ei + NUM_EDGES;
    const float* W1 = (const float*)d_in[2];
    const float* b1 = (const float*)d_in[3];
    const float* W2 = (const float*)d_in[4];
    const float* b2 = (const float*)d_in[5];
    const float* W3 = (const float*)d_in[6];
    const float* b3 = (const float*)d_in[7];
    const float* fc1_w = (const float*)d_in[8];
    const float* fc1_b = (const float*)d_in[9];
    const float* fc2_w = (const float*)d_in[10];
    const float* fc2_b = (const float*)d_in[11];
    float* out = (float*)d_out;

    // workspace layout (re-poisoned 0xAA each call; ctrl region zeroed below)
    char* wsb = (char*)d_ws;
    int* bar = (int*)wsb;                                   // 64 B
    int* bucket_cursor = bar + 16;                          // 1 KB
    float* fc1accum = (float*)(bucket_cursor + 256);        // 16 KB
    int* binned = (int*)(wsb + CTRL_BYTES);                 // 5.24 MB
    unsigned short* csr = (unsigned short*)(binned + NB * BUCKET_CAP);  // 2.62 MB
    int* rowstart = (int*)(csr + NB * BUCKET_CAP);          // 256 KB
    int* rowend = rowstart + N_NODES;                       // 256 KB
    float* dinv = (float*)(rowend + N_NODES);               // 256 KB
    half8* p0 = (half8*)(dinv + N_NODES);                   // 2 MB
    half8* pA = p0 + (size_t)N_NODES * 2;                   // 4 MB
    half8* pB = pA + (size_t)N_NODES * 4;                   // 4 MB
    float* h3 = (float*)(pB + (size_t)N_NODES * 4);         // 8 MB

    hipMemsetAsync(d_ws, 0, CTRL_BYTES, stream);
    mega_kernel<<<NBLK, 256, 0, stream>>>(x, src, dst, W1, b1, W2, b2, W3, b3,
                                          fc1_w, fc1_b, fc2_w, fc2_b,
                                          bar, bucket_cursor, fc1accum,
                                          binned, csr, rowstart, rowend, dinv,
                                          p0, pA, pB, h3, out);
}

// Round 4
// 403.971 us; speedup vs baseline: 2.4146x; 2.4146x over previous
//
#include <hip/hip_runtime.h>

#define N_NODES 65536
#define IN_FEAT 16
#define HIDDEN 32
#define NUM_EDGES 1048576
#define NUM_GRAPHS 16
#define NODES_PER_GRAPH 4096
#define FC1_IN (NODES_PER_GRAPH * HIDDEN) /* 131072 */
#define FC1_OUT 256
#define FC2_OUT 64
#define FC1_KCHUNK 128
#define FC1_BLOCKS (FC1_IN / FC1_KCHUNK) /* 1024 */
#define NB 256          /* buckets = dst>>8 */
#define BUCKET_CAP 5120 /* mean 4096, sd 64 -> 16 sigma headroom */
#define EPB_A 4096      /* edges per phase-A block */

typedef _Float16 half8 __attribute__((ext_vector_type(8)));  // 16 B

// ---- init bucket cursors to fixed-capacity bases + zero fc1 accumulator ----
__global__ void initcur_kernel(int* __restrict__ bucket_cursor, float* __restrict__ fc1accum) {
    int t = threadIdx.x;
    bucket_cursor[t] = t * BUCKET_CAP;
#pragma unroll
    for (int i = 0; i < NUM_GRAPHS * FC1_OUT / 256; i++) fc1accum[t + 256 * i] = 0.f;
}

// ---- phase A: bin edges by dst>>8 with chunk-contiguous writes ----
__global__ void binA_kernel(const int* __restrict__ src, const int* __restrict__ dst,
                            int* __restrict__ bucket_cursor, int* __restrict__ binned) {
    __shared__ int hist[NB];
    __shared__ int base[NB];
    __shared__ int cur[NB];
    int t = threadIdx.x;
    hist[t] = 0;
    __syncthreads();
    int e0 = blockIdx.x * EPB_A;
    int s[16], d[16];
#pragma unroll
    for (int i = 0; i < 16; i++) {
        int e = e0 + t + 256 * i;
        s[i] = src[e];
        d[i] = dst[e];
    }
#pragma unroll
    for (int i = 0; i < 16; i++) atomicAdd(&hist[d[i] >> 8], 1);
    __syncthreads();
    base[t] = atomicAdd(&bucket_cursor[t], hist[t]);
    cur[t] = 0;
    __syncthreads();
#pragma unroll
    for (int i = 0; i < 16; i++) {
        int b = d[i] >> 8;
        int r = atomicAdd(&cur[b], 1);
        binned[base[b] + r] = s[i] | ((d[i] & 255) << 16);
    }
}

// ---- phase B: per-bucket LDS counting sort by dst low byte (512 threads) ----
// emits csr (ushort), rowstart/rowend, dinv, and p0 = x*dinv in fp16.
__global__ void sortB_kernel(const int* __restrict__ bucket_cursor, const int* __restrict__ binned,
                             unsigned short* __restrict__ csr, int* __restrict__ rowstart,
                             int* __restrict__ rowend, float* __restrict__ dinv,
                             const float* __restrict__ x, half8* __restrict__ p0) {
    __shared__ int hist[NB];
    __shared__ int scanbuf[NB];
    __shared__ int start[NB];
    __shared__ int cur[NB];
    int t = threadIdx.x;  // 0..511
    int b = blockIdx.x;
    int bbase = b * BUCKET_CAP;
    int cnt = bucket_cursor[b] - bbase;
    if (t < NB) hist[t] = 0;
    __syncthreads();
    for (int i = t; i < cnt; i += 512) atomicAdd(&hist[binned[bbase + i] >> 16], 1);
    __syncthreads();
    int v = 0;
    if (t < NB) {
        v = hist[t];
        scanbuf[t] = v;
    }
    __syncthreads();
    for (int off = 1; off < NB; off <<= 1) {
        int y = 0;
        if (t < NB && t >= off) y = scanbuf[t - off];
        __syncthreads();
        if (t < NB) scanbuf[t] += y;
        __syncthreads();
    }
    if (t < NB) {
        start[t] = scanbuf[t] - v;  // exclusive prefix within bucket
        cur[t] = 0;
    }
    __syncthreads();
    for (int i = t; i < cnt; i += 512) {
        int p = binned[bbase + i];
        int dl = p >> 16;
        int r = atomicAdd(&cur[dl], 1);
        csr[bbase + start[dl] + r] = (unsigned short)(p & 0xFFFF);
    }
    if (t < NB) {
        int n = b * NB + t;
        int excl = start[t];
        rowstart[n] = bbase + excl;
        rowend[n] = bbase + excl + v;
        dinv[n] = rsqrtf((float)v + 1.0f);
    }
    // p0 prescale: 512 threads = 256 nodes x 2 half8-chunks
    {
        int nl = t >> 1;
        int qq = t & 1;
        int n = b * NB + nl;
        float di = rsqrtf((float)hist[nl] + 1.0f);
        const float4* x4 = (const float4*)x;
        float4 a = x4[(size_t)n * 4 + 2 * qq];
        float4 c = x4[(size_t)n * 4 + 2 * qq + 1];
        half8 hh;
        hh[0] = (_Float16)(a.x * di); hh[1] = (_Float16)(a.y * di);
        hh[2] = (_Float16)(a.z * di); hh[3] = (_Float16)(a.w * di);
        hh[4] = (_Float16)(c.x * di); hh[5] = (_Float16)(c.y * di);
        hh[6] = (_Float16)(c.z * di); hh[7] = (_Float16)(c.w * di);
        p0[(size_t)n * 2 + qq] = hh;
    }
}

// ---- fused gather+matmul, quad-grain (no mid-kernel block barrier) ----
// q[n] = sum_{s in N(n)} p[s] + p[n]  (fp32 accum of fp16 rows, in registers)
// v = relu(dinv[n]*(q[n]@W) + b);  LAST: store fp32 h3, else p_next = v*dinv fp16.
// The F8 lanes of a node run identical-length loops -> butterfly shfl_xor
// (masks 1,2; stays in-quad) redistributes q; each lane computes its own
// contiguous 8/F8-float4 output group and stores its own half8 chunk(s).
template <int FIN, bool LAST>
__global__ void gmm_kernel(const int* __restrict__ rowstart, const int* __restrict__ rowend,
                           const unsigned short* __restrict__ csr, const half8* __restrict__ p,
                           const float* __restrict__ W, const float* __restrict__ bias,
                           const float* __restrict__ dinv, void* __restrict__ outp) {
    constexpr int F8 = FIN / 8;        // half8 chunks per input row: 2 or 4
    constexpr int LOG2F8 = (FIN == 16) ? 1 : 2;
    constexpr int NOUT4 = 8 / F8;      // float4 output groups per lane: 4 or 2
    __shared__ float4 Ws4[FIN * 8];    // W[FIN][32] as float4
    __shared__ float4 bs4[8];
    int t = threadIdx.x;
    for (int i = t; i < FIN * 8; i += 256) Ws4[i] = ((const float4*)W)[i];
    if (t < 8) bs4[t] = ((const float4*)bias)[t];
    __syncthreads();  // only barrier: before divergent work, no straggler cost

    int f8 = t & (F8 - 1);
    int n = (blockIdx.x * 256 + t) >> LOG2F8;

    // ---- gather stage ----
    half8 self = p[(size_t)n * F8 + f8];
    float acc[8];
#pragma unroll
    for (int e = 0; e < 8; e++) acc[e] = (float)self[e];
    int beg = rowstart[n];
    int end = rowend[n];
    int i = beg;
    for (; i + 8 <= end; i += 8) {
        int s[8];
#pragma unroll
        for (int u = 0; u < 8; u++) s[u] = csr[i + u];
        half8 a[8];
#pragma unroll
        for (int u = 0; u < 8; u++) a[u] = p[(size_t)s[u] * F8 + f8];
#pragma unroll
        for (int u = 0; u < 8; u++)
#pragma unroll
            for (int e = 0; e < 8; e++) acc[e] += (float)a[u][e];
    }
    if (i + 4 <= end) {
        int s[4];
#pragma unroll
        for (int u = 0; u < 4; u++) s[u] = csr[i + u];
        half8 a[4];
#pragma unroll
        for (int u = 0; u < 4; u++) a[u] = p[(size_t)s[u] * F8 + f8];
#pragma unroll
        for (int u = 0; u < 4; u++)
#pragma unroll
            for (int e = 0; e < 8; e++) acc[e] += (float)a[u][e];
        i += 4;
    }
    for (; i < end; i++) {
        half8 a = p[(size_t)csr[i] * F8 + f8];
#pragma unroll
        for (int e = 0; e < 8; e++) acc[e] += (float)a[e];
    }

    // ---- in-quad butterfly: lane gains all FIN q-features ----
    float a1[8], a2[8], a3[8];
#pragma unroll
    for (int e = 0; e < 8; e++) a1[e] = __shfl_xor(acc[e], 1);
    if (F8 == 4) {
#pragma unroll
        for (int e = 0; e < 8; e++) a2[e] = __shfl_xor(acc[e], 2);
#pragma unroll
        for (int e = 0; e < 8; e++) a3[e] = __shfl_xor(a1[e], 2);
    }

    // ---- per-lane matmul: outputs [f8*NOUT4*4 .. +NOUT4*4) ----
    int fo0 = f8 * NOUT4;
    float4 o4[NOUT4];
#pragma unroll
    for (int j = 0; j < NOUT4; j++) o4[j] = make_float4(0.f, 0.f, 0.f, 0.f);

#define MM_CHUNK(AR, C)                                               \
    {                                                                 \
        int c_ = (C);                                                 \
        _Pragma("unroll") for (int e = 0; e < 8; e++) {               \
            int fi = c_ * 8 + e;                                      \
            float r = (AR)[e];                                        \
            _Pragma("unroll") for (int j = 0; j < NOUT4; j++) {       \
                float4 wv = Ws4[fi * 8 + fo0 + j];                    \
                o4[j].x += r * wv.x;                                  \
                o4[j].y += r * wv.y;                                  \
                o4[j].z += r * wv.z;                                  \
                o4[j].w += r * wv.w;                                  \
            }                                                         \
        }                                                             \
    }

    MM_CHUNK(acc, f8)
    MM_CHUNK(a1, f8 ^ 1)
    if (F8 == 4) {
        MM_CHUNK(a2, f8 ^ 2)
        MM_CHUNK(a3, f8 ^ 3)
    }
#undef MM_CHUNK

    // ---- epilogue ----
    float di = dinv[n];
    float4 v4[NOUT4];
#pragma unroll
    for (int j = 0; j < NOUT4; j++) {
        float4 bb = bs4[fo0 + j];
        float4 v;
        v.x = o4[j].x * di + bb.x;
        v.y = o4[j].y * di + bb.y;
        v.z = o4[j].z * di + bb.z;
        v.w = o4[j].w * di + bb.w;
        v.x = v.x > 0.f ? v.x : 0.f;
        v.y = v.y > 0.f ? v.y : 0.f;
        v.z = v.z > 0.f ? v.z : 0.f;
        v.w = v.w > 0.f ? v.w : 0.f;
        v4[j] = v;
    }
    if (LAST) {
        float4* o = (float4*)outp;
#pragma unroll
        for (int j = 0; j < NOUT4; j++) o[(size_t)n * 8 + fo0 + j] = v4[j];
    } else {
        half8* o = (half8*)outp;
#pragma unroll
        for (int pr = 0; pr < NOUT4 / 2; pr++) {
            float4 lo = v4[2 * pr], hi = v4[2 * pr + 1];
            half8 hh;
            hh[0] = (_Float16)(lo.x * di); hh[1] = (_Float16)(lo.y * di);
            hh[2] = (_Float16)(lo.z * di); hh[3] = (_Float16)(lo.w * di);
            hh[4] = (_Float16)(hi.x * di); hh[5] = (_Float16)(hi.y * di);
            hh[6] = (_Float16)(hi.z * di); hh[7] = (_Float16)(hi.w * di);
            o[(size_t)n * 4 + fo0 / 2 + pr] = hh;
        }
    }
}

// ---- fc1: partial dot over one kchunk, atomic-accumulate into fc1accum[16][256] ----
// fc1accum is 16 KB (L2-resident); ~4096 addresses x ~1k atomics each.
__global__ void fc1_kernel(const float* __restrict__ h3, const float* __restrict__ w,
                           float* __restrict__ fc1accum) {
    __shared__ float hs[NUM_GRAPHS * FC1_KCHUNK];  // 8 KB
    int t = threadIdx.x;
    int kbase = blockIdx.x * FC1_KCHUNK;
    for (int i = t; i < NUM_GRAPHS * FC1_KCHUNK; i += 256) {
        int g = i >> 7;  // FC1_KCHUNK == 128
        int kk = i & 127;
        hs[i] = h3[(size_t)g * FC1_IN + kbase + kk];
    }
    __syncthreads();
    int kl = t & 3;
    int c = t >> 2;
    float4 acc[NUM_GRAPHS];
#pragma unroll
    for (int g = 0; g < NUM_GRAPHS; g++) acc[g] = make_float4(0.f, 0.f, 0.f, 0.f);
    const float4* w4 = (const float4*)w;  // row k = 64 float4
    for (int i0 = 0; i0 < FC1_KCHUNK / 4; i0 += 4) {
        float4 wv[4];
#pragma unroll
        for (int u = 0; u < 4; u++)
            wv[u] = w4[(size_t)(kbase + kl + 4 * (i0 + u)) * (FC1_OUT / 4) + c];
#pragma unroll
        for (int u = 0; u < 4; u++) {
            int kk = kl + 4 * (i0 + u);
#pragma unroll
            for (int g = 0; g < NUM_GRAPHS; g++) {
                float hg = hs[g * FC1_KCHUNK + kk];
                acc[g].x += hg * wv[u].x;
                acc[g].y += hg * wv[u].y;
                acc[g].z += hg * wv[u].z;
                acc[g].w += hg * wv[u].w;
            }
        }
    }
#pragma unroll
    for (int g = 0; g < NUM_GRAPHS; g++) {
        acc[g].x += __shfl_xor(acc[g].x, 1);
        acc[g].y += __shfl_xor(acc[g].y, 1);
        acc[g].z += __shfl_xor(acc[g].z, 1);
        acc[g].w += __shfl_xor(acc[g].w, 1);
        acc[g].x += __shfl_xor(acc[g].x, 2);
        acc[g].y += __shfl_xor(acc[g].y, 2);
        acc[g].z += __shfl_xor(acc[g].z, 2);
        acc[g].w += __shfl_xor(acc[g].w, 2);
    }
    if (kl == 0) {
#pragma unroll
        for (int g = 0; g < NUM_GRAPHS; g++) {
            float* dstp = &fc1accum[g * FC1_OUT + c * 4];
            atomicAdd(dstp + 0, acc[g].x);
            atomicAdd(dstp + 1, acc[g].y);
            atomicAdd(dstp + 2, acc[g].z);
            atomicAdd(dstp + 3, acc[g].w);
        }
    }
}

// ---- fc2: bias+relu on fc1accum, then 256->64 matmul ----
__global__ void fc2_kernel(const float* __restrict__ fc1accum, const float* __restrict__ fc1_b,
                           const float* __restrict__ w2, const float* __restrict__ b2,
                           float* __restrict__ out) {
    int g = blockIdx.x;
    int j = threadIdx.x;  // 0..63
    __shared__ float vs[FC1_OUT];
    for (int k = j; k < FC1_OUT; k += 64) {
        float s = fc1accum[g * FC1_OUT + k] + fc1_b[k];
        vs[k] = s > 0.f ? s : 0.f;
    }
    __syncthreads();
    float acc = b2[j];
    for (int k = 0; k < FC1_OUT; k++) acc += vs[k] * w2[k * FC2_OUT + j];
    out[g * FC2_OUT + j] = acc;
}

extern "C" void kernel_launch(void* const* d_in, const int* in_sizes, int n_in,
                              void* d_out, int out_size, void* d_ws, size_t ws_size,
                              hipStream_t stream) {
    const float* x = (const float*)d_in[0];
    const int* ei = (const int*)d_in[1];
    const int* src = ei;
    const int* dst = ei + NUM_EDGES;
    const float* W1 = (const float*)d_in[2];
    const float* b1 = (const float*)d_in[3];
    const float* W2 = (const float*)d_in[4];
    const float* b2 = (const float*)d_in[5];
    const float* W3 = (const float*)d_in[6];
    const float* b3 = (const float*)d_in[7];
    const float* fc1_w = (const float*)d_in[8];
    const float* fc1_b = (const float*)d_in[9];
    const float* fc2_w = (const float*)d_in[10];
    const float* fc2_b = (const float*)d_in[11];
    float* out = (float*)d_out;

    // workspace layout (re-poisoned 0xAA each call)
    int* bucket_cursor = (int*)d_ws;                       // 1 KB
    float* fc1accum = (float*)(bucket_cursor + 256);       // 16 KB
    int* binned = (int*)(fc1accum + NUM_GRAPHS * FC1_OUT); // 5.24 MB
    unsigned short* csr = (unsigned short*)(binned + NB * BUCKET_CAP);  // 2.62 MB
    int* rowstart = (int*)(csr + NB * BUCKET_CAP);         // 256 KB
    int* rowend = rowstart + N_NODES;                      // 256 KB
    float* dinv = (float*)(rowend + N_NODES);              // 256 KB
    half8* p0 = (half8*)(dinv + N_NODES);                  // N*16 fp16 = 2 MB
    half8* pA = (half8*)(p0 + (size_t)N_NODES * 2);        // N*32 fp16 = 4 MB
    half8* pB = (half8*)(pA + (size_t)N_NODES * 4);        // N*32 fp16 = 4 MB
    float* h3 = (float*)(pB + (size_t)N_NODES * 4);        // N*32 f32 = 8 MB

    initcur_kernel<<<1, 256, 0, stream>>>(bucket_cursor, fc1accum);
    binA_kernel<<<NUM_EDGES / EPB_A, 256, 0, stream>>>(src, dst, bucket_cursor, binned);
    sortB_kernel<<<NB, 512, 0, stream>>>(bucket_cursor, binned, csr, rowstart, rowend, dinv, x, p0);

    // layer 1: fused gather(16-feat p0) + matmul W1 -> pA (fp16)
    gmm_kernel<IN_FEAT, false><<<N_NODES * 2 / 256, 256, 0, stream>>>(
        rowstart, rowend, csr, p0, W1, b1, dinv, pA);
    // layer 2: fused gather(32-feat pA) + matmul W2 -> pB (fp16)
    gmm_kernel<HIDDEN, false><<<N_NODES * 4 / 256, 256, 0, stream>>>(
        rowstart, rowend, csr, pA, W2, b2, dinv, pB);
    // layer 3: fused gather(32-feat pB) + matmul W3 -> h3 (fp32)
    gmm_kernel<HIDDEN, true><<<N_NODES * 4 / 256, 256, 0, stream>>>(
        rowstart, rowend, csr, pB, W3, b3, dinv, h3);

    fc1_kernel<<<FC1_BLOCKS, 256, 0, stream>>>(h3, fc1_w, fc1accum);
    fc2_kernel<<<NUM_GRAPHS, 64, 0, stream>>>(fc1accum, fc1_b, fc2_w, fc2_b, out);
}

// Round 5
// 312.995 us; speedup vs baseline: 3.1164x; 1.2907x over previous
//
#include <hip/hip_runtime.h>

#define N_NODES 65536
#define IN_FEAT 16
#define HIDDEN 32
#define NUM_EDGES 1048576
#define NUM_GRAPHS 16
#define NODES_PER_GRAPH 4096
#define FC1_IN (NODES_PER_GRAPH * HIDDEN) /* 131072 */
#define FC1_OUT 256
#define FC2_OUT 64
#define FC1_KCHUNK 128
#define FC1_BLOCKS (FC1_IN / FC1_KCHUNK) /* 1024 */
#define NB 256          /* buckets = dst>>8 */
#define BUCKET_CAP 5120 /* mean 4096, sd 64 -> 16 sigma headroom */
#define EPB_A 4096      /* edges per phase-A block */

typedef _Float16 half8 __attribute__((ext_vector_type(8)));  // 16 B

// ---- init bucket cursors to fixed-capacity bases ----
__global__ void initcur_kernel(int* __restrict__ bucket_cursor) {
    bucket_cursor[threadIdx.x] = threadIdx.x * BUCKET_CAP;
}

// ---- phase A: bin edges by dst>>8 with chunk-contiguous writes ----
__global__ void binA_kernel(const int* __restrict__ src, const int* __restrict__ dst,
                            int* __restrict__ bucket_cursor, int* __restrict__ binned) {
    __shared__ int hist[NB];
    __shared__ int base[NB];
    __shared__ int cur[NB];
    int t = threadIdx.x;
    hist[t] = 0;
    __syncthreads();
    int e0 = blockIdx.x * EPB_A;
    int s[16], d[16];
#pragma unroll
    for (int i = 0; i < 16; i++) {
        int e = e0 + t + 256 * i;
        s[i] = src[e];
        d[i] = dst[e];
    }
#pragma unroll
    for (int i = 0; i < 16; i++) atomicAdd(&hist[d[i] >> 8], 1);
    __syncthreads();
    base[t] = atomicAdd(&bucket_cursor[t], hist[t]);
    cur[t] = 0;
    __syncthreads();
#pragma unroll
    for (int i = 0; i < 16; i++) {
        int b = d[i] >> 8;
        int r = atomicAdd(&cur[b], 1);
        binned[base[b] + r] = s[i] | ((d[i] & 255) << 16);
    }
}

// ---- phase B: per-bucket LDS counting sort by dst low byte (512 threads) ----
// emits csr (ushort), rowstart/rowend, dinv, and p0 = x*dinv in fp16.
__global__ void sortB_kernel(const int* __restrict__ bucket_cursor, const int* __restrict__ binned,
                             unsigned short* __restrict__ csr, int* __restrict__ rowstart,
                             int* __restrict__ rowend, float* __restrict__ dinv,
                             const float* __restrict__ x, half8* __restrict__ p0) {
    __shared__ int hist[NB];
    __shared__ int scanbuf[NB];
    __shared__ int start[NB];
    __shared__ int cur[NB];
    int t = threadIdx.x;  // 0..511
    int b = blockIdx.x;
    int bbase = b * BUCKET_CAP;
    int cnt = bucket_cursor[b] - bbase;
    if (t < NB) hist[t] = 0;
    __syncthreads();
    for (int i = t; i < cnt; i += 512) atomicAdd(&hist[binned[bbase + i] >> 16], 1);
    __syncthreads();
    int v = 0;
    if (t < NB) {
        v = hist[t];
        scanbuf[t] = v;
    }
    __syncthreads();
    for (int off = 1; off < NB; off <<= 1) {
        int y = 0;
        if (t < NB && t >= off) y = scanbuf[t - off];
        __syncthreads();
        if (t < NB) scanbuf[t] += y;
        __syncthreads();
    }
    if (t < NB) {
        start[t] = scanbuf[t] - v;  // exclusive prefix within bucket
        cur[t] = 0;
    }
    __syncthreads();
    for (int i = t; i < cnt; i += 512) {
        int p = binned[bbase + i];
        int dl = p >> 16;
        int r = atomicAdd(&cur[dl], 1);
        csr[bbase + start[dl] + r] = (unsigned short)(p & 0xFFFF);
    }
    if (t < NB) {
        int n = b * NB + t;
        int excl = start[t];
        rowstart[n] = bbase + excl;
        rowend[n] = bbase + excl + v;
        dinv[n] = rsqrtf((float)v + 1.0f);
    }
    // p0 prescale: 512 threads = 256 nodes x 2 half8-chunks
    {
        int nl = t >> 1;
        int qq = t & 1;
        int n = b * NB + nl;
        float di = rsqrtf((float)hist[nl] + 1.0f);
        const float4* x4 = (const float4*)x;
        float4 a = x4[(size_t)n * 4 + 2 * qq];
        float4 c = x4[(size_t)n * 4 + 2 * qq + 1];
        half8 hh;
        hh[0] = (_Float16)(a.x * di); hh[1] = (_Float16)(a.y * di);
        hh[2] = (_Float16)(a.z * di); hh[3] = (_Float16)(a.w * di);
        hh[4] = (_Float16)(c.x * di); hh[5] = (_Float16)(c.y * di);
        hh[6] = (_Float16)(c.z * di); hh[7] = (_Float16)(c.w * di);
        p0[(size_t)n * 2 + qq] = hh;
    }
}

// ---- fused gather+matmul, quad-grain (no mid-kernel block barrier) ----
template <int FIN, bool LAST>
__global__ void gmm_kernel(const int* __restrict__ rowstart, const int* __restrict__ rowend,
                           const unsigned short* __restrict__ csr, const half8* __restrict__ p,
                           const float* __restrict__ W, const float* __restrict__ bias,
                           const float* __restrict__ dinv, void* __restrict__ outp) {
    constexpr int F8 = FIN / 8;        // half8 chunks per input row: 2 or 4
    constexpr int LOG2F8 = (FIN == 16) ? 1 : 2;
    constexpr int NOUT4 = 8 / F8;      // float4 output groups per lane: 4 or 2
    __shared__ float4 Ws4[FIN * 8];    // W[FIN][32] as float4
    __shared__ float4 bs4[8];
    int t = threadIdx.x;
    for (int i = t; i < FIN * 8; i += 256) Ws4[i] = ((const float4*)W)[i];
    if (t < 8) bs4[t] = ((const float4*)bias)[t];
    __syncthreads();  // only barrier: before divergent work, no straggler cost

    int f8 = t & (F8 - 1);
    int n = (blockIdx.x * 256 + t) >> LOG2F8;

    // ---- gather stage ----
    half8 self = p[(size_t)n * F8 + f8];
    float acc[8];
#pragma unroll
    for (int e = 0; e < 8; e++) acc[e] = (float)self[e];
    int beg = rowstart[n];
    int end = rowend[n];
    int i = beg;
    for (; i + 8 <= end; i += 8) {
        int s[8];
#pragma unroll
        for (int u = 0; u < 8; u++) s[u] = csr[i + u];
        half8 a[8];
#pragma unroll
        for (int u = 0; u < 8; u++) a[u] = p[(size_t)s[u] * F8 + f8];
#pragma unroll
        for (int u = 0; u < 8; u++)
#pragma unroll
            for (int e = 0; e < 8; e++) acc[e] += (float)a[u][e];
    }
    if (i + 4 <= end) {
        int s[4];
#pragma unroll
        for (int u = 0; u < 4; u++) s[u] = csr[i + u];
        half8 a[4];
#pragma unroll
        for (int u = 0; u < 4; u++) a[u] = p[(size_t)s[u] * F8 + f8];
#pragma unroll
        for (int u = 0; u < 4; u++)
#pragma unroll
            for (int e = 0; e < 8; e++) acc[e] += (float)a[u][e];
        i += 4;
    }
    for (; i < end; i++) {
        half8 a = p[(size_t)csr[i] * F8 + f8];
#pragma unroll
        for (int e = 0; e < 8; e++) acc[e] += (float)a[e];
    }

    // ---- in-quad butterfly: lane gains all FIN q-features ----
    float a1[8], a2[8], a3[8];
#pragma unroll
    for (int e = 0; e < 8; e++) a1[e] = __shfl_xor(acc[e], 1);
    if (F8 == 4) {
#pragma unroll
        for (int e = 0; e < 8; e++) a2[e] = __shfl_xor(acc[e], 2);
#pragma unroll
        for (int e = 0; e < 8; e++) a3[e] = __shfl_xor(a1[e], 2);
    }

    // ---- per-lane matmul: outputs [f8*NOUT4*4 .. +NOUT4*4) ----
    int fo0 = f8 * NOUT4;
    float4 o4[NOUT4];
#pragma unroll
    for (int j = 0; j < NOUT4; j++) o4[j] = make_float4(0.f, 0.f, 0.f, 0.f);

#define MM_CHUNK(AR, C)                                               \
    {                                                                 \
        int c_ = (C);                                                 \
        _Pragma("unroll") for (int e = 0; e < 8; e++) {               \
            int fi = c_ * 8 + e;                                      \
            float r = (AR)[e];                                        \
            _Pragma("unroll") for (int j = 0; j < NOUT4; j++) {       \
                float4 wv = Ws4[fi * 8 + fo0 + j];                    \
                o4[j].x += r * wv.x;                                  \
                o4[j].y += r * wv.y;                                  \
                o4[j].z += r * wv.z;                                  \
                o4[j].w += r * wv.w;                                  \
            }                                                         \
        }                                                             \
    }

    MM_CHUNK(acc, f8)
    MM_CHUNK(a1, f8 ^ 1)
    if (F8 == 4) {
        MM_CHUNK(a2, f8 ^ 2)
        MM_CHUNK(a3, f8 ^ 3)
    }
#undef MM_CHUNK

    // ---- epilogue ----
    float di = dinv[n];
    float4 v4[NOUT4];
#pragma unroll
    for (int j = 0; j < NOUT4; j++) {
        float4 bb = bs4[fo0 + j];
        float4 v;
        v.x = o4[j].x * di + bb.x;
        v.y = o4[j].y * di + bb.y;
        v.z = o4[j].z * di + bb.z;
        v.w = o4[j].w * di + bb.w;
        v.x = v.x > 0.f ? v.x : 0.f;
        v.y = v.y > 0.f ? v.y : 0.f;
        v.z = v.z > 0.f ? v.z : 0.f;
        v.w = v.w > 0.f ? v.w : 0.f;
        v4[j] = v;
    }
    if (LAST) {
        float4* o = (float4*)outp;
#pragma unroll
        for (int j = 0; j < NOUT4; j++) o[(size_t)n * 8 + fo0 + j] = v4[j];
    } else {
        half8* o = (half8*)outp;
#pragma unroll
        for (int pr = 0; pr < NOUT4 / 2; pr++) {
            float4 lo = v4[2 * pr], hi = v4[2 * pr + 1];
            half8 hh;
            hh[0] = (_Float16)(lo.x * di); hh[1] = (_Float16)(lo.y * di);
            hh[2] = (_Float16)(lo.z * di); hh[3] = (_Float16)(lo.w * di);
            hh[4] = (_Float16)(hi.x * di); hh[5] = (_Float16)(hi.y * di);
            hh[6] = (_Float16)(hi.z * di); hh[7] = (_Float16)(hi.w * di);
            o[(size_t)n * 4 + fo0 / 2 + pr] = hh;
        }
    }
}

// ---- fc1 partials with two-bank software pipeline (8 loads in flight/bank) ----
// part[b][g][j] = sum_{k in chunk b} h3[g][k]*w[k][j]
__global__ __launch_bounds__(256) void fc1_kernel(const float* __restrict__ h3,
                                                  const float* __restrict__ w,
                                                  float* __restrict__ part) {
    __shared__ float hs[NUM_GRAPHS * FC1_KCHUNK];  // 8 KB
    int t = threadIdx.x;
    int kbase = blockIdx.x * FC1_KCHUNK;
    for (int i = t; i < NUM_GRAPHS * FC1_KCHUNK; i += 256) {
        int g = i >> 7;  // FC1_KCHUNK == 128
        int kk = i & 127;
        hs[i] = h3[(size_t)g * FC1_IN + kbase + kk];
    }
    __syncthreads();
    int kl = t & 3;
    int c = t >> 2;  // 0..63: float4 column
    const float4* w4 = (const float4*)w;  // row k = 64 float4
    float4 acc[NUM_GRAPHS];
#pragma unroll
    for (int g = 0; g < NUM_GRAPHS; g++) acc[g] = make_float4(0.f, 0.f, 0.f, 0.f);

    // thread owns rows k = kbase + kl + 4*i, i = 0..31; process in 4 groups of 8
    float4 wa[8], wb[8];
#define LOADW(BUF, I0)                                                        \
    _Pragma("unroll") for (int u = 0; u < 8; u++)                             \
        (BUF)[u] = w4[(size_t)(kbase + kl + 4 * ((I0) + u)) * (FC1_OUT / 4) + c];
#define COMPW(BUF, I0)                                                        \
    _Pragma("unroll") for (int u = 0; u < 8; u++) {                           \
        int kk = kl + 4 * ((I0) + u);                                         \
        _Pragma("unroll") for (int g = 0; g < NUM_GRAPHS; g++) {              \
            float hg = hs[g * FC1_KCHUNK + kk];                               \
            acc[g].x += hg * (BUF)[u].x;                                      \
            acc[g].y += hg * (BUF)[u].y;                                      \
            acc[g].z += hg * (BUF)[u].z;                                      \
            acc[g].w += hg * (BUF)[u].w;                                      \
        }                                                                     \
    }

    LOADW(wa, 0)
    LOADW(wb, 8)
    COMPW(wa, 0)
    LOADW(wa, 16)
    COMPW(wb, 8)
    LOADW(wb, 24)
    COMPW(wa, 16)
    COMPW(wb, 24)
#undef LOADW
#undef COMPW

#pragma unroll
    for (int g = 0; g < NUM_GRAPHS; g++) {
        acc[g].x += __shfl_xor(acc[g].x, 1);
        acc[g].y += __shfl_xor(acc[g].y, 1);
        acc[g].z += __shfl_xor(acc[g].z, 1);
        acc[g].w += __shfl_xor(acc[g].w, 1);
        acc[g].x += __shfl_xor(acc[g].x, 2);
        acc[g].y += __shfl_xor(acc[g].y, 2);
        acc[g].z += __shfl_xor(acc[g].z, 2);
        acc[g].w += __shfl_xor(acc[g].w, 2);
    }
    if (kl == 0) {
        float4* p4 = (float4*)part;
#pragma unroll
        for (int g = 0; g < NUM_GRAPHS; g++)
            p4[(size_t)blockIdx.x * (NUM_GRAPHS * FC1_OUT / 4) + g * (FC1_OUT / 4) + c] = acc[g];
    }
}

// ---- reduce partials -> partial8[bq][j']; no atomics, no memset needed ----
__global__ void reduce_kernel(const float* __restrict__ part, float* __restrict__ partial8) {
    int tid = blockIdx.x * 256 + threadIdx.x;  // 32768 threads
    int j = tid & 4095;
    int bq = tid >> 12;  // 0..7
    float s = 0.f;
#pragma unroll 8
    for (int u = 0; u < FC1_BLOCKS / 8; u++)
        s += part[(size_t)(bq * (FC1_BLOCKS / 8) + u) * (NUM_GRAPHS * FC1_OUT) + j];
    partial8[bq * (NUM_GRAPHS * FC1_OUT) + j] = s;
}

// ---- fc2: folds the 8 partials, bias+relu, then 256->64 matmul ----
__global__ void fc2_kernel(const float* __restrict__ partial8, const float* __restrict__ fc1_b,
                           const float* __restrict__ w2, const float* __restrict__ b2,
                           float* __restrict__ out) {
    int g = blockIdx.x;
    int j = threadIdx.x;  // 0..63
    __shared__ float vs[FC1_OUT];
    for (int k = j; k < FC1_OUT; k += 64) {
        float s = fc1_b[k];
#pragma unroll
        for (int bq = 0; bq < 8; bq++)
            s += partial8[bq * (NUM_GRAPHS * FC1_OUT) + g * FC1_OUT + k];
        vs[k] = s > 0.f ? s : 0.f;
    }
    __syncthreads();
    float acc = b2[j];
    for (int k = 0; k < FC1_OUT; k++) acc += vs[k] * w2[k * FC2_OUT + j];
    out[g * FC2_OUT + j] = acc;
}

extern "C" void kernel_launch(void* const* d_in, const int* in_sizes, int n_in,
                              void* d_out, int out_size, void* d_ws, size_t ws_size,
                              hipStream_t stream) {
    const float* x = (const float*)d_in[0];
    const int* ei = (const int*)d_in[1];
    const int* src = ei;
    const int* dst = ei + NUM_EDGES;
    const float* W1 = (const float*)d_in[2];
    const float* b1 = (const float*)d_in[3];
    const float* W2 = (const float*)d_in[4];
    const float* b2 = (const float*)d_in[5];
    const float* W3 = (const float*)d_in[6];
    const float* b3 = (const float*)d_in[7];
    const float* fc1_w = (const float*)d_in[8];
    const float* fc1_b = (const float*)d_in[9];
    const float* fc2_w = (const float*)d_in[10];
    const float* fc2_b = (const float*)d_in[11];
    float* out = (float*)d_out;

    // workspace layout (re-poisoned 0xAA each call)
    int* bucket_cursor = (int*)d_ws;                       // 1 KB
    int* binned = bucket_cursor + 256;                     // 5.24 MB
    unsigned short* csr = (unsigned short*)(binned + NB * BUCKET_CAP);  // 2.62 MB
    int* rowstart = (int*)(csr + NB * BUCKET_CAP);         // 256 KB
    int* rowend = rowstart + N_NODES;                      // 256 KB
    float* dinv = (float*)(rowend + N_NODES);              // 256 KB
    half8* p0 = (half8*)(dinv + N_NODES);                  // N*16 fp16 = 2 MB
    half8* pA = (half8*)(p0 + (size_t)N_NODES * 2);        // N*32 fp16 = 4 MB
    half8* pB = (half8*)(pA + (size_t)N_NODES * 4);        // N*32 fp16 = 4 MB
    float* h3 = (float*)(pB + (size_t)N_NODES * 4);        // N*32 f32 = 8 MB
    float* part = h3 + (size_t)N_NODES * HIDDEN;           // 16 MB
    float* partial8 = part + (size_t)FC1_BLOCKS * NUM_GRAPHS * FC1_OUT;  // 128 KB

    initcur_kernel<<<1, 256, 0, stream>>>(bucket_cursor);
    binA_kernel<<<NUM_EDGES / EPB_A, 256, 0, stream>>>(src, dst, bucket_cursor, binned);
    sortB_kernel<<<NB, 512, 0, stream>>>(bucket_cursor, binned, csr, rowstart, rowend, dinv, x, p0);

    // layer 1: fused gather(16-feat p0) + matmul W1 -> pA (fp16)
    gmm_kernel<IN_FEAT, false><<<N_NODES * 2 / 256, 256, 0, stream>>>(
        rowstart, rowend, csr, p0, W1, b1, dinv, pA);
    // layer 2: fused gather(32-feat pA) + matmul W2 -> pB (fp16)
    gmm_kernel<HIDDEN, false><<<N_NODES * 4 / 256, 256, 0, stream>>>(
        rowstart, rowend, csr, pA, W2, b2, dinv, pB);
    // layer 3: fused gather(32-feat pB) + matmul W3 -> h3 (fp32)
    gmm_kernel<HIDDEN, true><<<N_NODES * 4 / 256, 256, 0, stream>>>(
        rowstart, rowend, csr, pB, W3, b3, dinv, h3);

    fc1_kernel<<<FC1_BLOCKS, 256, 0, stream>>>(h3, fc1_w, part);
    reduce_kernel<<<128, 256, 0, stream>>>(part, partial8);
    fc2_kernel<<<NUM_GRAPHS, 64, 0, stream>>>(partial8, fc1_b, fc2_w, fc2_b, out);
}

// Round 7
// 295.903 us; speedup vs baseline: 3.2964x; 1.0578x over previous
//
#include <hip/hip_runtime.h>

#define N_NODES 65536
#define IN_FEAT 16
#define HIDDEN 32
#define NUM_EDGES 1048576
#define NUM_GRAPHS 16
#define NODES_PER_GRAPH 4096
#define FC1_IN (NODES_PER_GRAPH * HIDDEN) /* 131072 */
#define FC1_OUT 256
#define FC2_OUT 64
#define FC1_KCHUNK 128
#define FC1_BLOCKS (FC1_IN / FC1_KCHUNK) /* 1024 */
#define RED_Q 16        /* reduce fan-in groups */
#define NB 256          /* buckets = dst>>8 */
#define BUCKET_CAP 5120 /* mean 4096, sd 64 -> 16 sigma headroom */
#define EPB_A 4096      /* edges per phase-A block */

typedef _Float16 half8 __attribute__((ext_vector_type(8)));  // 16 B
typedef float floatx4 __attribute__((ext_vector_type(4)));   // native vec for nt builtins

__device__ __forceinline__ float4 ntload4(const float4* p) {
    floatx4 v = __builtin_nontemporal_load((const floatx4*)p);
    return make_float4(v.x, v.y, v.z, v.w);
}
__device__ __forceinline__ int ntloadi(const int* p) {
    return __builtin_nontemporal_load(p);
}
__device__ __forceinline__ float ntloadf(const float* p) {
    return __builtin_nontemporal_load(p);
}

// ---- init bucket cursors to fixed-capacity bases ----
__global__ void initcur_kernel(int* __restrict__ bucket_cursor) {
    bucket_cursor[threadIdx.x] = threadIdx.x * BUCKET_CAP;
}

// ---- phase A: bin edges by dst>>8 with chunk-contiguous writes ----
// src/dst are stream-once: non-temporal (don't evict L3 lines for them).
__global__ void binA_kernel(const int* __restrict__ src, const int* __restrict__ dst,
                            int* __restrict__ bucket_cursor, int* __restrict__ binned) {
    __shared__ int hist[NB];
    __shared__ int base[NB];
    __shared__ int cur[NB];
    int t = threadIdx.x;
    hist[t] = 0;
    __syncthreads();
    int e0 = blockIdx.x * EPB_A;
    int s[16], d[16];
#pragma unroll
    for (int i = 0; i < 16; i++) {
        int e = e0 + t + 256 * i;
        s[i] = ntloadi(src + e);
        d[i] = ntloadi(dst + e);
    }
#pragma unroll
    for (int i = 0; i < 16; i++) atomicAdd(&hist[d[i] >> 8], 1);
    __syncthreads();
    base[t] = atomicAdd(&bucket_cursor[t], hist[t]);
    cur[t] = 0;
    __syncthreads();
#pragma unroll
    for (int i = 0; i < 16; i++) {
        int b = d[i] >> 8;
        int r = atomicAdd(&cur[b], 1);
        binned[base[b] + r] = s[i] | ((d[i] & 255) << 16);
    }
}

// ---- phase B: per-bucket LDS counting sort by dst low byte (512 threads) ----
// emits csr (ushort), rowstart/rowend, dinv, and p0 = x*dinv in fp16.
__global__ void sortB_kernel(const int* __restrict__ bucket_cursor, const int* __restrict__ binned,
                             unsigned short* __restrict__ csr, int* __restrict__ rowstart,
                             int* __restrict__ rowend, float* __restrict__ dinv,
                             const float* __restrict__ x, half8* __restrict__ p0) {
    __shared__ int hist[NB];
    __shared__ int scanbuf[NB];
    __shared__ int start[NB];
    __shared__ int cur[NB];
    int t = threadIdx.x;  // 0..511
    int b = blockIdx.x;
    int bbase = b * BUCKET_CAP;
    int cnt = bucket_cursor[b] - bbase;
    if (t < NB) hist[t] = 0;
    __syncthreads();
    for (int i = t; i < cnt; i += 512) atomicAdd(&hist[binned[bbase + i] >> 16], 1);
    __syncthreads();
    int v = 0;
    if (t < NB) {
        v = hist[t];
        scanbuf[t] = v;
    }
    __syncthreads();
    for (int off = 1; off < NB; off <<= 1) {
        int y = 0;
        if (t < NB && t >= off) y = scanbuf[t - off];
        __syncthreads();
        if (t < NB) scanbuf[t] += y;
        __syncthreads();
    }
    if (t < NB) {
        start[t] = scanbuf[t] - v;  // exclusive prefix within bucket
        cur[t] = 0;
    }
    __syncthreads();
    for (int i = t; i < cnt; i += 512) {
        int p = binned[bbase + i];
        int dl = p >> 16;
        int r = atomicAdd(&cur[dl], 1);
        csr[bbase + start[dl] + r] = (unsigned short)(p & 0xFFFF);
    }
    if (t < NB) {
        int n = b * NB + t;
        int excl = start[t];
        rowstart[n] = bbase + excl;
        rowend[n] = bbase + excl + v;
        dinv[n] = rsqrtf((float)v + 1.0f);
    }
    // p0 prescale: 512 threads = 256 nodes x 2 half8-chunks
    {
        int nl = t >> 1;
        int qq = t & 1;
        int n = b * NB + nl;
        float di = rsqrtf((float)hist[nl] + 1.0f);
        const float4* x4 = (const float4*)x;
        float4 a = x4[(size_t)n * 4 + 2 * qq];
        float4 c = x4[(size_t)n * 4 + 2 * qq + 1];
        half8 hh;
        hh[0] = (_Float16)(a.x * di); hh[1] = (_Float16)(a.y * di);
        hh[2] = (_Float16)(a.z * di); hh[3] = (_Float16)(a.w * di);
        hh[4] = (_Float16)(c.x * di); hh[5] = (_Float16)(c.y * di);
        hh[6] = (_Float16)(c.z * di); hh[7] = (_Float16)(c.w * di);
        p0[(size_t)n * 2 + qq] = hh;
    }
}

// ---- fused gather+matmul, quad-grain (no mid-kernel block barrier) ----
template <int FIN, bool LAST>
__global__ void gmm_kernel(const int* __restrict__ rowstart, const int* __restrict__ rowend,
                           const unsigned short* __restrict__ csr, const half8* __restrict__ p,
                           const float* __restrict__ W, const float* __restrict__ bias,
                           const float* __restrict__ dinv, void* __restrict__ outp) {
    constexpr int F8 = FIN / 8;        // half8 chunks per input row: 2 or 4
    constexpr int LOG2F8 = (FIN == 16) ? 1 : 2;
    constexpr int NOUT4 = 8 / F8;      // float4 output groups per lane: 4 or 2
    __shared__ float4 Ws4[FIN * 8];    // W[FIN][32] as float4
    __shared__ float4 bs4[8];
    int t = threadIdx.x;
    for (int i = t; i < FIN * 8; i += 256) Ws4[i] = ((const float4*)W)[i];
    if (t < 8) bs4[t] = ((const float4*)bias)[t];
    __syncthreads();  // only barrier: before divergent work, no straggler cost

    int f8 = t & (F8 - 1);
    int n = (blockIdx.x * 256 + t) >> LOG2F8;

    // ---- gather stage ----
    half8 self = p[(size_t)n * F8 + f8];
    float acc[8];
#pragma unroll
    for (int e = 0; e < 8; e++) acc[e] = (float)self[e];
    int beg = rowstart[n];
    int end = rowend[n];
    int i = beg;
    for (; i + 8 <= end; i += 8) {
        int s[8];
#pragma unroll
        for (int u = 0; u < 8; u++) s[u] = csr[i + u];
        half8 a[8];
#pragma unroll
        for (int u = 0; u < 8; u++) a[u] = p[(size_t)s[u] * F8 + f8];
#pragma unroll
        for (int u = 0; u < 8; u++)
#pragma unroll
            for (int e = 0; e < 8; e++) acc[e] += (float)a[u][e];
    }
    if (i + 4 <= end) {
        int s[4];
#pragma unroll
        for (int u = 0; u < 4; u++) s[u] = csr[i + u];
        half8 a[4];
#pragma unroll
        for (int u = 0; u < 4; u++) a[u] = p[(size_t)s[u] * F8 + f8];
#pragma unroll
        for (int u = 0; u < 4; u++)
#pragma unroll
            for (int e = 0; e < 8; e++) acc[e] += (float)a[u][e];
        i += 4;
    }
    for (; i < end; i++) {
        half8 a = p[(size_t)csr[i] * F8 + f8];
#pragma unroll
        for (int e = 0; e < 8; e++) acc[e] += (float)a[e];
    }

    // ---- in-quad butterfly: lane gains all FIN q-features ----
    float a1[8], a2[8], a3[8];
#pragma unroll
    for (int e = 0; e < 8; e++) a1[e] = __shfl_xor(acc[e], 1);
    if (F8 == 4) {
#pragma unroll
        for (int e = 0; e < 8; e++) a2[e] = __shfl_xor(acc[e], 2);
#pragma unroll
        for (int e = 0; e < 8; e++) a3[e] = __shfl_xor(a1[e], 2);
    }

    // ---- per-lane matmul: outputs [f8*NOUT4*4 .. +NOUT4*4) ----
    int fo0 = f8 * NOUT4;
    float4 o4[NOUT4];
#pragma unroll
    for (int j = 0; j < NOUT4; j++) o4[j] = make_float4(0.f, 0.f, 0.f, 0.f);

#define MM_CHUNK(AR, C)                                               \
    {                                                                 \
        int c_ = (C);                                                 \
        _Pragma("unroll") for (int e = 0; e < 8; e++) {               \
            int fi = c_ * 8 + e;                                      \
            float r = (AR)[e];                                        \
            _Pragma("unroll") for (int j = 0; j < NOUT4; j++) {       \
                float4 wv = Ws4[fi * 8 + fo0 + j];                    \
                o4[j].x += r * wv.x;                                  \
                o4[j].y += r * wv.y;                                  \
                o4[j].z += r * wv.z;                                  \
                o4[j].w += r * wv.w;                                  \
            }                                                         \
        }                                                             \
    }

    MM_CHUNK(acc, f8)
    MM_CHUNK(a1, f8 ^ 1)
    if (F8 == 4) {
        MM_CHUNK(a2, f8 ^ 2)
        MM_CHUNK(a3, f8 ^ 3)
    }
#undef MM_CHUNK

    // ---- epilogue ----
    float di = dinv[n];
    float4 v4[NOUT4];
#pragma unroll
    for (int j = 0; j < NOUT4; j++) {
        float4 bb = bs4[fo0 + j];
        float4 v;
        v.x = o4[j].x * di + bb.x;
        v.y = o4[j].y * di + bb.y;
        v.z = o4[j].z * di + bb.z;
        v.w = o4[j].w * di + bb.w;
        v.x = v.x > 0.f ? v.x : 0.f;
        v.y = v.y > 0.f ? v.y : 0.f;
        v.z = v.z > 0.f ? v.z : 0.f;
        v.w = v.w > 0.f ? v.w : 0.f;
        v4[j] = v;
    }
    if (LAST) {
        float4* o = (float4*)outp;
#pragma unroll
        for (int j = 0; j < NOUT4; j++) o[(size_t)n * 8 + fo0 + j] = v4[j];
    } else {
        half8* o = (half8*)outp;
#pragma unroll
        for (int pr = 0; pr < NOUT4 / 2; pr++) {
            float4 lo = v4[2 * pr], hi = v4[2 * pr + 1];
            half8 hh;
            hh[0] = (_Float16)(lo.x * di); hh[1] = (_Float16)(lo.y * di);
            hh[2] = (_Float16)(lo.z * di); hh[3] = (_Float16)(lo.w * di);
            hh[4] = (_Float16)(hi.x * di); hh[5] = (_Float16)(hi.y * di);
            hh[6] = (_Float16)(hi.z * di); hh[7] = (_Float16)(hi.w * di);
            o[(size_t)n * 4 + fo0 / 2 + pr] = hh;
        }
    }
}

// ---- fc1 partials; fc1_w and h3 are stream-once -> non-temporal loads ----
// part[b][g][j] = sum_{k in chunk b} h3[g][k]*w[k][j]
__global__ __launch_bounds__(256) void fc1_kernel(const float* __restrict__ h3,
                                                  const float* __restrict__ w,
                                                  float* __restrict__ part) {
    __shared__ float hs[NUM_GRAPHS * FC1_KCHUNK];  // 8 KB
    int t = threadIdx.x;
    int kbase = blockIdx.x * FC1_KCHUNK;
    for (int i = t; i < NUM_GRAPHS * FC1_KCHUNK; i += 256) {
        int g = i >> 7;  // FC1_KCHUNK == 128
        int kk = i & 127;
        hs[i] = ntloadf(h3 + (size_t)g * FC1_IN + kbase + kk);
    }
    __syncthreads();
    int kl = t & 3;
    int c = t >> 2;  // 0..63: float4 column
    const float4* w4 = (const float4*)w;  // row k = 64 float4
    float4 acc[NUM_GRAPHS];
#pragma unroll
    for (int g = 0; g < NUM_GRAPHS; g++) acc[g] = make_float4(0.f, 0.f, 0.f, 0.f);

    // thread owns rows k = kbase + kl + 4*i, i = 0..31; two-bank pipeline
    float4 wa[8], wb[8];
#define LOADW(BUF, I0)                                                        \
    _Pragma("unroll") for (int u = 0; u < 8; u++)                             \
        (BUF)[u] = ntload4(&w4[(size_t)(kbase + kl + 4 * ((I0) + u)) * (FC1_OUT / 4) + c]);
#define COMPW(BUF, I0)                                                        \
    _Pragma("unroll") for (int u = 0; u < 8; u++) {                           \
        int kk = kl + 4 * ((I0) + u);                                         \
        _Pragma("unroll") for (int g = 0; g < NUM_GRAPHS; g++) {              \
            float hg = hs[g * FC1_KCHUNK + kk];                               \
            acc[g].x += hg * (BUF)[u].x;                                      \
            acc[g].y += hg * (BUF)[u].y;                                      \
            acc[g].z += hg * (BUF)[u].z;                                      \
            acc[g].w += hg * (BUF)[u].w;                                      \
        }                                                                     \
    }

    LOADW(wa, 0)
    LOADW(wb, 8)
    COMPW(wa, 0)
    LOADW(wa, 16)
    COMPW(wb, 8)
    LOADW(wb, 24)
    COMPW(wa, 16)
    COMPW(wb, 24)
#undef LOADW
#undef COMPW

#pragma unroll
    for (int g = 0; g < NUM_GRAPHS; g++) {
        acc[g].x += __shfl_xor(acc[g].x, 1);
        acc[g].y += __shfl_xor(acc[g].y, 1);
        acc[g].z += __shfl_xor(acc[g].z, 1);
        acc[g].w += __shfl_xor(acc[g].w, 1);
        acc[g].x += __shfl_xor(acc[g].x, 2);
        acc[g].y += __shfl_xor(acc[g].y, 2);
        acc[g].z += __shfl_xor(acc[g].z, 2);
        acc[g].w += __shfl_xor(acc[g].w, 2);
    }
    if (kl == 0) {
        float4* p4 = (float4*)part;
#pragma unroll
        for (int g = 0; g < NUM_GRAPHS; g++)
            p4[(size_t)blockIdx.x * (NUM_GRAPHS * FC1_OUT / 4) + g * (FC1_OUT / 4) + c] = acc[g];
    }
}

// ---- reduce partials -> partial16[bq][j']; 256 blocks (full GPU) ----
__global__ void reduce_kernel(const float* __restrict__ part, float* __restrict__ partial16) {
    int tid = blockIdx.x * 256 + threadIdx.x;  // 65536 threads
    int j = tid & 4095;
    int bq = tid >> 12;  // 0..15
    float s = 0.f;
#pragma unroll 8
    for (int u = 0; u < FC1_BLOCKS / RED_Q; u++)
        s += part[(size_t)(bq * (FC1_BLOCKS / RED_Q) + u) * (NUM_GRAPHS * FC1_OUT) + j];
    partial16[bq * (NUM_GRAPHS * FC1_OUT) + j] = s;
}

// ---- fc2: folds the 16 partials, bias+relu, then 256->64 matmul ----
__global__ void fc2_kernel(const float* __restrict__ partial16, const float* __restrict__ fc1_b,
                           const float* __restrict__ w2, const float* __restrict__ b2,
                           float* __restrict__ out) {
    int g = blockIdx.x;
    int j = threadIdx.x;  // 0..63
    __shared__ float vs[FC1_OUT];
    for (int k = j; k < FC1_OUT; k += 64) {
        float s = fc1_b[k];
#pragma unroll
        for (int bq = 0; bq < RED_Q; bq++)
            s += partial16[bq * (NUM_GRAPHS * FC1_OUT) + g * FC1_OUT + k];
        vs[k] = s > 0.f ? s : 0.f;
    }
    __syncthreads();
    float acc = b2[j];
    for (int k = 0; k < FC1_OUT; k++) acc += vs[k] * w2[k * FC2_OUT + j];
    out[g * FC2_OUT + j] = acc;
}

extern "C" void kernel_launch(void* const* d_in, const int* in_sizes, int n_in,
                              void* d_out, int out_size, void* d_ws, size_t ws_size,
                              hipStream_t stream) {
    const float* x = (const float*)d_in[0];
    const int* ei = (const int*)d_in[1];
    const int* src = ei;
    const int* dst = ei + NUM_EDGES;
    const float* W1 = (const float*)d_in[2];
    const float* b1 = (const float*)d_in[3];
    const float* W2 = (const float*)d_in[4];
    const float* b2 = (const float*)d_in[5];
    const float* W3 = (const float*)d_in[6];
    const float* b3 = (const float*)d_in[7];
    const float* fc1_w = (const float*)d_in[8];
    const float* fc1_b = (const float*)d_in[9];
    const float* fc2_w = (const float*)d_in[10];
    const float* fc2_b = (const float*)d_in[11];
    float* out = (float*)d_out;

    // workspace layout (re-poisoned 0xAA each call)
    int* bucket_cursor = (int*)d_ws;                       // 1 KB
    int* binned = bucket_cursor + 256;                     // 5.24 MB
    unsigned short* csr = (unsigned short*)(binned + NB * BUCKET_CAP);  // 2.62 MB
    int* rowstart = (int*)(csr + NB * BUCKET_CAP);         // 256 KB
    int* rowend = rowstart + N_NODES;                      // 256 KB
    float* dinv = (float*)(rowend + N_NODES);              // 256 KB
    half8* p0 = (half8*)(dinv + N_NODES);                  // N*16 fp16 = 2 MB
    half8* pA = (half8*)(p0 + (size_t)N_NODES * 2);        // N*32 fp16 = 4 MB
    half8* pB = (half8*)(pA + (size_t)N_NODES * 4);        // N*32 fp16 = 4 MB
    float* h3 = (float*)(pB + (size_t)N_NODES * 4);        // N*32 f32 = 8 MB
    float* part = h3 + (size_t)N_NODES * HIDDEN;           // 16 MB
    float* partial16 = part + (size_t)FC1_BLOCKS * NUM_GRAPHS * FC1_OUT;  // 256 KB

    initcur_kernel<<<1, 256, 0, stream>>>(bucket_cursor);
    binA_kernel<<<NUM_EDGES / EPB_A, 256, 0, stream>>>(src, dst, bucket_cursor, binned);
    sortB_kernel<<<NB, 512, 0, stream>>>(bucket_cursor, binned, csr, rowstart, rowend, dinv, x, p0);

    // layer 1: fused gather(16-feat p0) + matmul W1 -> pA (fp16)
    gmm_kernel<IN_FEAT, false><<<N_NODES * 2 / 256, 256, 0, stream>>>(
        rowstart, rowend, csr, p0, W1, b1, dinv, pA);
    // layer 2: fused gather(32-feat pA) + matmul W2 -> pB (fp16)
    gmm_kernel<HIDDEN, false><<<N_NODES * 4 / 256, 256, 0, stream>>>(
        rowstart, rowend, csr, pA, W2, b2, dinv, pB);
    // layer 3: fused gather(32-feat pB) + matmul W3 -> h3 (fp32)
    gmm_kernel<HIDDEN, true><<<N_NODES * 4 / 256, 256, 0, stream>>>(
        rowstart, rowend, csr, pB, W3, b3, dinv, h3);

    fc1_kernel<<<FC1_BLOCKS, 256, 0, stream>>>(h3, fc1_w, part);
    reduce_kernel<<<256, 256, 0, stream>>>(part, partial16);
    fc2_kernel<<<NUM_GRAPHS, 64, 0, stream>>>(partial16, fc1_b, fc2_w, fc2_b, out);
}